// Round 18
// baseline (179.052 us; speedup 1.0000x reference)
//
#include <hip/hip_runtime.h>

#define NP 100000
#define NE 1600000
#define SD 64      // STATE_DIM
#define HID 32
#define MSG 64
#define NP_PAD 100352
#define NTILE (NP / 16)          // 6250
#define TILE_BLOCKS ((NTILE + 3) / 4)     // 1563
#define BINSZ 256
#define NBIN ((NP + BINSZ - 1) / BINSZ)   // 391
#define MAXE 5632                // bin edges: mean 4096, std ~64 -> 24 sigma
#define EPW 8192
#define NWG ((NE + EPW - 1) / EPW)        // 196

typedef float v4f __attribute__((ext_vector_type(4)));
typedef short v4s __attribute__((ext_vector_type(4)));
typedef short v8s __attribute__((ext_vector_type(8)));
typedef __bf16 v8bf __attribute__((ext_vector_type(8)));

// weight-frag ids (each frag = 64 lanes x v8s = 1 KiB):
// edge MLP: 0-3 w1s hi, 4-7 w1s lo, 8-11 w1d hi, 12-15 w1d lo,
//           16-17 w2 hi[t], 18-19 w2 lo, 20-23 w3 hi[t], 24-27 w3 lo
// node MLP: 28-35 oW1 hi, 36-43 oW1 lo, 44-45 oW2 hi, 46-47 oW2 lo,
//           48-51 oW3 hi[t], 52-55 oW3 lo
#define WQ_FRAGS 56

__device__ __forceinline__ v4f MFMA32(v8s a, v8s b, v4f c) {
  return __builtin_amdgcn_mfma_f32_16x16x32_bf16(
      __builtin_bit_cast(v8bf, a), __builtin_bit_cast(v8bf, b), c, 0, 0, 0);
}

__device__ __forceinline__ short f2bf(float f) {   // HW RNE cvt
  return __builtin_bit_cast(short, (__bf16)f);
}
__device__ __forceinline__ float bf2f(short s) {
  unsigned u = ((unsigned)(unsigned short)s) << 16;
  return __builtin_bit_cast(float, u);
}

// 3-term split-bf16 product: C += Ah*Bh + Ah*Bl + Al*Bh (error ~2^-17 rel)
__device__ __forceinline__ v4f mfma3(v8s ah, v8s al, v8s bh, v8s bl, v4f c) {
  c = MFMA32(al, bh, c);
  c = MFMA32(ah, bl, c);
  c = MFMA32(ah, bh, c);
  return c;
}

// A-frag (hi/lo) from row-major W[K][ld]: A[m][k] = W[k][m0+l15]
__device__ __forceinline__ void load_wfrag(const float* __restrict__ W, int ld,
                                           int kb, int m0, int lq, int l15,
                                           v8s* hi, v8s* lo) {
  v8s h, l;
#pragma unroll
  for (int j = 0; j < 8; ++j) {
    int k = kb + ((j < 4) ? (4 * lq + j) : (16 + 4 * lq + (j - 4)));
    float v = W[k * ld + m0 + l15];
    short hb = f2bf(v);
    h[j] = hb;
    l[j] = f2bf(v - bf2f(hb));
  }
  *hi = h;
  *lo = l;
}

// split two v4f halves into one split B-frag (no relu)
__device__ __forceinline__ void split8(v4f a, v4f b, v8s* hi, v8s* lo) {
  v8s h, l;
#pragma unroll
  for (int j = 0; j < 4; ++j) {
    short ha = f2bf(a[j]); h[j] = ha; l[j] = f2bf(a[j] - bf2f(ha));
    short hb = f2bf(b[j]); h[j + 4] = hb; l[j + 4] = f2bf(b[j] - bf2f(hb));
  }
  *hi = h;
  *lo = l;
}

// B-frag (hi/lo) from an f32 feature row
__device__ __forceinline__ void load_xfrag(const float* xs, int kb, int lq,
                                           v8s* hi, v8s* lo) {
  v4f a = *reinterpret_cast<const v4f*>(xs + kb + 4 * lq);
  v4f b = *reinterpret_cast<const v4f*>(xs + kb + 16 + 4 * lq);
  split8(a, b, hi, lo);
}

// D blocks -> next-layer split B-frag with relu
__device__ __forceinline__ void chain_frag(v4f d0, v4f d1, v8s* hi, v8s* lo) {
  v4f a, b;
#pragma unroll
  for (int j = 0; j < 4; ++j) {
    a[j] = fmaxf(d0[j], 0.f);
    b[j] = fmaxf(d1[j], 0.f);
  }
  split8(a, b, hi, lo);
}

// D blocks -> bf16 B-frag with relu, hi only (per-edge-independent error)
__device__ __forceinline__ v8s chain_hi(v4f d0, v4f d1) {
  v8s h;
#pragma unroll
  for (int j = 0; j < 4; ++j) {
    h[j] = f2bf(fmaxf(d0[j], 0.f));
    h[j + 4] = f2bf(fmaxf(d1[j], 0.f));
  }
  return h;
}

// ---------------- setup: bin_count (blocks 0..NWG-1) | prew (block NWG) |
//                  prep (blocks NWG+1 ..) -- all independent ----------------
__global__ __launch_bounds__(256, 2) void setup_kernel(
    const float* __restrict__ x, const int* __restrict__ ei,
    const float* __restrict__ mW1, const float* __restrict__ mb1,
    const float* __restrict__ mW2, const float* __restrict__ mW3,
    const float* __restrict__ oW1, const float* __restrict__ oW2,
    const float* __restrict__ oW3,
    int* __restrict__ gOff, short* __restrict__ wqs,
    float* __restrict__ h1d_buf, short* __restrict__ h1s_buf) {
  __shared__ int cnt[NBIN];
  const int blk = blockIdx.x;

  if (blk < NWG) {
    // ---- per-(bin, WG) histogram ----
    for (int i = threadIdx.x; i < NBIN; i += 256) cnt[i] = 0;
    __syncthreads();
    const int e0 = blk * EPW;
    const int e1 = (e0 + EPW < NE) ? e0 + EPW : NE;
    for (int e = e0 + threadIdx.x; e < e1; e += 256)
      atomicAdd(&cnt[ei[NE + e] >> 8], 1);
    __syncthreads();
    for (int i = threadIdx.x; i < NBIN; i += 256) gOff[i * NWG + blk] = cnt[i];
    return;
  }

  const int lane = threadIdx.x & 63;
  const int l15 = lane & 15;
  const int lq = lane >> 4;

  if (blk == NWG) {
    // ---- weight prequantization (64 threads) ----
    if (threadIdx.x >= 64) return;
    v8s* wq = reinterpret_cast<v8s*>(wqs);
    v8s h, l;
#pragma unroll
    for (int t = 0; t < 2; ++t)
#pragma unroll
      for (int kc = 0; kc < 2; ++kc) {
        load_wfrag(mW1, HID, kc * 32, t * 16, lq, l15, &h, &l);
        wq[(t * 2 + kc) * 64 + lane] = h;
        wq[(4 + t * 2 + kc) * 64 + lane] = l;
        load_wfrag(mW1, HID, 64 + kc * 32, t * 16, lq, l15, &h, &l);
        wq[(8 + t * 2 + kc) * 64 + lane] = h;
        wq[(12 + t * 2 + kc) * 64 + lane] = l;
      }
#pragma unroll
    for (int t = 0; t < 2; ++t) {
      load_wfrag(mW2, HID, 0, t * 16, lq, l15, &h, &l);
      wq[(16 + t) * 64 + lane] = h;
      wq[(18 + t) * 64 + lane] = l;
    }
#pragma unroll
    for (int t = 0; t < 4; ++t) {
      load_wfrag(mW3, MSG, 0, t * 16, lq, l15, &h, &l);
      wq[(20 + t) * 64 + lane] = h;
      wq[(24 + t) * 64 + lane] = l;
    }
#pragma unroll
    for (int t = 0; t < 2; ++t)
#pragma unroll
      for (int kc = 0; kc < 4; ++kc) {
        load_wfrag(oW1, HID, kc * 32, t * 16, lq, l15, &h, &l);
        wq[(28 + t * 4 + kc) * 64 + lane] = h;
        wq[(36 + t * 4 + kc) * 64 + lane] = l;
      }
#pragma unroll
    for (int t = 0; t < 2; ++t) {
      load_wfrag(oW2, HID, 0, t * 16, lq, l15, &h, &l);
      wq[(44 + t) * 64 + lane] = h;
      wq[(46 + t) * 64 + lane] = l;
    }
#pragma unroll
    for (int t = 0; t < 4; ++t) {
      load_wfrag(oW3, SD, 0, t * 16, lq, l15, &h, &l);
      wq[(48 + t) * 64 + lane] = h;
      wq[(52 + t) * 64 + lane] = l;
    }
    return;
  }

  // ---- prep: h1d (f32, split-exact) + h1s (bf16) per node, 16 nodes/wave.
  const int tile = ((blk - NWG - 1) * 256 + (int)threadIdx.x) >> 6;
  if (tile >= NTILE) return;
  const int node = tile * 16 + l15;

  v4f d0, d1, s0 = {0.f, 0.f, 0.f, 0.f}, s1 = {0.f, 0.f, 0.f, 0.f};
#pragma unroll
  for (int q = 0; q < 4; ++q) {
    d0[q] = mb1[4 * lq + q];
    d1[q] = mb1[16 + 4 * lq + q];
  }
#pragma unroll
  for (int kc = 0; kc < 2; ++kc) {
    v8s xh, xl, wh, wl;
    load_xfrag(x + (size_t)node * SD, kc * 32, lq, &xh, &xl);
    load_wfrag(mW1, HID, 64 + kc * 32, 0, lq, l15, &wh, &wl);
    d0 = mfma3(wh, wl, xh, xl, d0);
    load_wfrag(mW1, HID, 64 + kc * 32, 16, lq, l15, &wh, &wl);
    d1 = mfma3(wh, wl, xh, xl, d1);
    load_wfrag(mW1, HID, kc * 32, 0, lq, l15, &wh, &wl);
    s0 = mfma3(wh, wl, xh, xl, s0);
    load_wfrag(mW1, HID, kc * 32, 16, lq, l15, &wh, &wl);
    s1 = mfma3(wh, wl, xh, xl, s1);
  }
  *reinterpret_cast<v4f*>(h1d_buf + (size_t)node * HID + 4 * lq) = d0;
  *reinterpret_cast<v4f*>(h1d_buf + (size_t)node * HID + 16 + 4 * lq) = d1;
  v4s q0, q1;
#pragma unroll
  for (int q = 0; q < 4; ++q) {
    q0[q] = f2bf(s0[q]);
    q1[q] = f2bf(s1[q]);
  }
  *reinterpret_cast<v4s*>(h1s_buf + (size_t)node * HID + 4 * lq) = q0;
  *reinterpret_cast<v4s*>(h1s_buf + (size_t)node * HID + 16 + 4 * lq) = q1;
}

// ---------------- CSR-lite build (bin-grouped pairs only) ----------------

// scan: int4-vectorized per-bin prefix + block-parallel scan of bin totals
__global__ __launch_bounds__(512) void scan_bins_kernel(
    int* __restrict__ gOff, int* __restrict__ binStart) {
  __shared__ int sh[512];
  const int b = threadIdx.x;
  int run = 0;
  if (b < NBIN) {
    int4* row = reinterpret_cast<int4*>(gOff + b * NWG);   // NWG % 4 == 0
#pragma unroll 4
    for (int i = 0; i < NWG / 4; ++i) {
      int4 v = row[i];
      int4 w;
      w.x = run; run += v.x;
      w.y = run; run += v.y;
      w.z = run; run += v.z;
      w.w = run; run += v.w;
      row[i] = w;
    }
  }
  sh[b] = run;   // bin total (0 for b >= NBIN)
  __syncthreads();
  for (int off = 1; off < 512; off <<= 1) {
    int a = (b >= off) ? sh[b - off] : 0;
    __syncthreads();
    sh[b] += a;
    __syncthreads();
  }
  const int excl = sh[b] - run;       // exclusive prefix of bin totals
  if (b <= NBIN) binStart[b] = excl;  // binStart[NBIN] == NE
  if (b < NBIN) {
    int4* row = reinterpret_cast<int4*>(gOff + b * NWG);
#pragma unroll 4
    for (int i = 0; i < NWG / 4; ++i) {
      int4 v = row[i];
      v.x += excl; v.y += excl; v.z += excl; v.w += excl;
      row[i] = v;
    }
  }
}

// scatter packed (src<<8 | dst&255) into bin-grouped array; 25 bits used.
// (bin,WG) regions exclusive -> every sector written by ONE workgroup.
__global__ __launch_bounds__(256) void bin_scatter_kernel(
    const int* __restrict__ ei, const int* __restrict__ gOff,
    unsigned* __restrict__ pairs) {
  __shared__ int cur[NBIN];
  const int w = blockIdx.x;
  for (int i = threadIdx.x; i < NBIN; i += 256) cur[i] = gOff[i * NWG + w];
  __syncthreads();
  const int e0 = w * EPW;
  const int e1 = (e0 + EPW < NE) ? e0 + EPW : NE;
  for (int e = e0 + threadIdx.x; e < e1; e += 256) {
    unsigned s = (unsigned)ei[e];
    unsigned d = (unsigned)ei[NE + e];
    int pos = atomicAdd(&cur[d >> 8], 1);
    pairs[pos] = (s << 8) | (d & (BINSZ - 1));
  }
}

// ---------------- bin-fused: LDS-local CSR build + R14 edge body ------------
// One WG per 256-node bin. Build {hist, excl, csr} in LDS (2 LDS atomics per
// edge), then 8 waves process the bin's nodes as A/B pairs (proven R14 body)
// with offsets/counts/indices from LDS -- the only global dependent load left
// on the per-node chain is the h1s gather itself.
__global__ __launch_bounds__(512, 4) void bin_fused_kernel(
    const short* __restrict__ h1s, const float* __restrict__ h1d_buf,
    const short* __restrict__ wqs, const unsigned* __restrict__ pairs,
    const int* __restrict__ binStart, const float* __restrict__ mb2,
    float* __restrict__ rsum, int* __restrict__ cntN) {
  __shared__ int hist[BINSZ];
  __shared__ int excl_s[BINSZ];
  __shared__ int cur[BINSZ];
  __shared__ int csr[MAXE];
  const int tid = threadIdx.x;
  const int b = blockIdx.x;
  const int p0 = binStart[b], p1 = binStart[b + 1];

  for (int i = tid; i < BINSZ; i += 512) hist[i] = 0;
  __syncthreads();
  for (int p = p0 + tid; p < p1; p += 512)
    atomicAdd(&hist[pairs[p] & (BINSZ - 1)], 1);
  __syncthreads();
  if (tid < BINSZ) excl_s[tid] = hist[tid];
  __syncthreads();
  for (int off = 1; off < BINSZ; off <<= 1) {
    int a = (tid < BINSZ && tid >= off) ? excl_s[tid - off] : 0;
    __syncthreads();
    if (tid < BINSZ) excl_s[tid] += a;
    __syncthreads();
  }
  if (tid < BINSZ) {
    int e = excl_s[tid] - hist[tid];   // exclusive
    excl_s[tid] = e;
    cur[tid] = e;
  }
  __syncthreads();
  for (int p = p0 + tid; p < p1; p += 512) {
    unsigned pr = pairs[p];
    int pos = atomicAdd(&cur[pr & (BINSZ - 1)], 1);
    if (pos < MAXE) csr[pos] = (int)(pr >> 8);
  }
  __syncthreads();

  // ---- processing: 8 waves x 32 nodes (16 A/B pairs) ----
  const int lane = tid & 63;
  const int l15 = lane & 15;
  const int lq = lane >> 4;
  const int wv = tid >> 6;
  const int nodeBase = b * BINSZ;
  const v8s* wq = reinterpret_cast<const v8s*>(wqs);

  const v8s w2h0 = wq[16 * 64 + lane], w2h1 = wq[17 * 64 + lane];
  const v8s w2l0 = wq[18 * 64 + lane], w2l1 = wq[19 * 64 + lane];
  v4f bb0, bb1;
#pragma unroll
  for (int q = 0; q < 4; ++q) {
    bb0[q] = mb2[4 * lq + q];
    bb1[q] = mb2[16 + 4 * lq + q];
  }

  for (int t = 0; t < 16; ++t) {
    const int nlA = wv * 32 + 2 * t;
    const int nlB = nlA + 1;
    const int nA = nodeBase + nlA;
    const int nB = nodeBase + nlB;
    const int offA = excl_s[nlA], cntA = hist[nlA];
    const int offB = excl_s[nlB], cntB = hist[nlB];
    const int ngA = (cntA + 15) >> 4;
    const int ngB = (cntB + 15) >> 4;
    const int ngM = ngA > ngB ? ngA : ngB;

    const v4f hA0 = *reinterpret_cast<const v4f*>(h1d_buf + (size_t)nA * HID + 4 * lq);
    const v4f hA1 = *reinterpret_cast<const v4f*>(h1d_buf + (size_t)nA * HID + 16 + 4 * lq);
    const v4f hB0 = *reinterpret_cast<const v4f*>(h1d_buf + (size_t)nB * HID + 4 * lq);
    const v4f hB1 = *reinterpret_cast<const v4f*>(h1d_buf + (size_t)nB * HID + 16 + 4 * lq);

    v4f rA0 = {0.f, 0.f, 0.f, 0.f}, rA1 = {0.f, 0.f, 0.f, 0.f};
    v4f rB0 = {0.f, 0.f, 0.f, 0.f}, rB1 = {0.f, 0.f, 0.f, 0.f};

    // prologue: group-0 indices (LDS) + gathers (global) for both nodes
    int sA = (l15 < cntA) ? csr[offA + l15] : 0;
    int sB = (l15 < cntB) ? csr[offB + l15] : 0;
    v4s aA = *reinterpret_cast<const v4s*>(h1s + (size_t)sA * HID + 4 * lq);
    v4s bA = *reinterpret_cast<const v4s*>(h1s + (size_t)sA * HID + 16 + 4 * lq);
    v4s aB = *reinterpret_cast<const v4s*>(h1s + (size_t)sB * HID + 4 * lq);
    v4s bB = *reinterpret_cast<const v4s*>(h1s + (size_t)sB * HID + 16 + 4 * lq);

    int remA = cntA, remB = cntB;
    for (int g = 0; g < ngM; ++g) {
      int sAn = (l15 < remA - 16) ? csr[offA + (g + 1) * 16 + l15] : 0;
      int sBn = (l15 < remB - 16) ? csr[offB + (g + 1) * 16 + l15] : 0;

      if (g < ngA) {
        v4f d0, d1;
#pragma unroll
        for (int q = 0; q < 4; ++q) {
          d0[q] = hA0[q] + bf2f(aA[q]);
          d1[q] = hA1[q] + bf2f(bA[q]);
        }
        v8s ph = chain_hi(d0, d1);
        v4f e0 = bb0, e1 = bb1;
        e0 = MFMA32(w2h0, ph, e0);
        e0 = MFMA32(w2l0, ph, e0);
        e1 = MFMA32(w2h1, ph, e1);
        e1 = MFMA32(w2l1, ph, e1);
        if (l15 < remA) {
#pragma unroll
          for (int j = 0; j < 4; ++j) {
            rA0[j] += fmaxf(e0[j], 0.f);
            rA1[j] += fmaxf(e1[j], 0.f);
          }
        }
      }
      aA = *reinterpret_cast<const v4s*>(h1s + (size_t)sAn * HID + 4 * lq);
      bA = *reinterpret_cast<const v4s*>(h1s + (size_t)sAn * HID + 16 + 4 * lq);

      if (g < ngB) {
        v4f d0, d1;
#pragma unroll
        for (int q = 0; q < 4; ++q) {
          d0[q] = hB0[q] + bf2f(aB[q]);
          d1[q] = hB1[q] + bf2f(bB[q]);
        }
        v8s ph = chain_hi(d0, d1);
        v4f e0 = bb0, e1 = bb1;
        e0 = MFMA32(w2h0, ph, e0);
        e0 = MFMA32(w2l0, ph, e0);
        e1 = MFMA32(w2h1, ph, e1);
        e1 = MFMA32(w2l1, ph, e1);
        if (l15 < remB) {
#pragma unroll
          for (int j = 0; j < 4; ++j) {
            rB0[j] += fmaxf(e0[j], 0.f);
            rB1[j] += fmaxf(e1[j], 0.f);
          }
        }
      }
      aB = *reinterpret_cast<const v4s*>(h1s + (size_t)sBn * HID + 4 * lq);
      bB = *reinterpret_cast<const v4s*>(h1s + (size_t)sBn * HID + 16 + 4 * lq);

      remA -= 16;
      remB -= 16;
    }

    // reduce relu-sums over the 16 slot-columns; write adjacent rsum rows
#pragma unroll
    for (int j = 0; j < 4; ++j) {
      float a = rA0[j], b2 = rA1[j], c = rB0[j], d = rB1[j];
      a += __shfl_xor(a, 1); a += __shfl_xor(a, 2);
      a += __shfl_xor(a, 4); a += __shfl_xor(a, 8);
      b2 += __shfl_xor(b2, 1); b2 += __shfl_xor(b2, 2);
      b2 += __shfl_xor(b2, 4); b2 += __shfl_xor(b2, 8);
      c += __shfl_xor(c, 1); c += __shfl_xor(c, 2);
      c += __shfl_xor(c, 4); c += __shfl_xor(c, 8);
      d += __shfl_xor(d, 1); d += __shfl_xor(d, 2);
      d += __shfl_xor(d, 4); d += __shfl_xor(d, 8);
      rA0[j] = a; rA1[j] = b2; rB0[j] = c; rB1[j] = d;
    }
    if (l15 == 0) {
      if (nA < NP) {
        *reinterpret_cast<v4f*>(rsum + (size_t)nA * HID + 4 * lq) = rA0;
        *reinterpret_cast<v4f*>(rsum + (size_t)nA * HID + 16 + 4 * lq) = rA1;
        if (lq == 0) cntN[nA] = cntA;
      }
      if (nB < NP) {
        *reinterpret_cast<v4f*>(rsum + (size_t)nB * HID + 4 * lq) = rB0;
        *reinterpret_cast<v4f*>(rsum + (size_t)nB * HID + 16 + 4 * lq) = rB1;
        if (lq == 0) cntN[nB] = cntB;
      }
    }
  }
}

// ---------------- fused tail: edge layer3 + full node MLP, 16 nodes/wave ----
__global__ __launch_bounds__(256, 2) void fused_tail_kernel(
    const float* __restrict__ x, const short* __restrict__ wqs,
    const float* __restrict__ rsum, const int* __restrict__ cntN,
    const float* __restrict__ mb3,
    const float* __restrict__ ob1, const float* __restrict__ ob2,
    const float* __restrict__ ob3,
    float* __restrict__ out) {
  const int lane = threadIdx.x & 63;
  const int l15 = lane & 15;
  const int lq = lane >> 4;
  const int tile = (blockIdx.x * 256 + threadIdx.x) >> 6;
  if (tile >= NTILE) return;
  const v8s* wq = reinterpret_cast<const v8s*>(wqs);

  const int node = tile * 16 + l15;
  const float fc = (float)cntN[node];

  // edge layer 3: msg = mW3^T r + fc*mb3
  v4f ra = *reinterpret_cast<const v4f*>(rsum + (size_t)node * HID + 4 * lq);
  v4f rb = *reinterpret_cast<const v4f*>(rsum + (size_t)node * HID + 16 + 4 * lq);
  v8s bh, bl;
  split8(ra, rb, &bh, &bl);

  v4f m[4];
#pragma unroll
  for (int t = 0; t < 4; ++t) {
    v4f c = {0.f, 0.f, 0.f, 0.f};
    c = mfma3(wq[(20 + t) * 64 + lane], wq[(24 + t) * 64 + lane], bh, bl, c);
#pragma unroll
    for (int q = 0; q < 4; ++q) c[q] += fc * mb3[t * 16 + 4 * lq + q];
    m[t] = c;
  }

  // node layer 1 on [x || msg]
  v4f d0, d1;
#pragma unroll
  for (int q = 0; q < 4; ++q) {
    d0[q] = ob1[4 * lq + q];
    d1[q] = ob1[16 + 4 * lq + q];
  }
#pragma unroll
  for (int kc = 0; kc < 2; ++kc) {
    v8s xh, xl;
    load_xfrag(x + (size_t)node * SD, kc * 32, lq, &xh, &xl);
    d0 = mfma3(wq[(28 + kc) * 64 + lane], wq[(36 + kc) * 64 + lane], xh, xl, d0);
    d1 = mfma3(wq[(32 + kc) * 64 + lane], wq[(40 + kc) * 64 + lane], xh, xl, d1);
  }
#pragma unroll
  for (int kc = 0; kc < 2; ++kc) {
    v8s mh, ml;
    split8(m[kc * 2], m[kc * 2 + 1], &mh, &ml);
    d0 = mfma3(wq[(30 + kc) * 64 + lane], wq[(38 + kc) * 64 + lane], mh, ml, d0);
    d1 = mfma3(wq[(34 + kc) * 64 + lane], wq[(42 + kc) * 64 + lane], mh, ml, d1);
  }

  // node layer 2
  v8s ph, pl;
  chain_frag(d0, d1, &ph, &pl);
  v4f e0, e1;
#pragma unroll
  for (int q = 0; q < 4; ++q) {
    e0[q] = ob2[4 * lq + q];
    e1[q] = ob2[16 + 4 * lq + q];
  }
  e0 = mfma3(wq[44 * 64 + lane], wq[46 * 64 + lane], ph, pl, e0);
  e1 = mfma3(wq[45 * 64 + lane], wq[47 * 64 + lane], ph, pl, e1);

  // node layer 3 -> out
  v8s rh, rl;
  chain_frag(e0, e1, &rh, &rl);
  float* orow = out + (size_t)node * SD;
#pragma unroll
  for (int t = 0; t < 4; ++t) {
    v4f c;
#pragma unroll
    for (int q = 0; q < 4; ++q) c[q] = ob3[t * 16 + 4 * lq + q];
    c = mfma3(wq[(48 + t) * 64 + lane], wq[(52 + t) * 64 + lane], rh, rl, c);
    *reinterpret_cast<v4f*>(orow + t * 16 + 4 * lq) = c;
  }
}

extern "C" void kernel_launch(void* const* d_in, const int* in_sizes, int n_in,
                              void* d_out, int out_size, void* d_ws,
                              size_t ws_size, hipStream_t stream) {
  const float* x = (const float*)d_in[0];
  const int* ei = (const int*)d_in[1];
  const float* mW1 = (const float*)d_in[2];
  const float* mb1 = (const float*)d_in[3];
  const float* mW2 = (const float*)d_in[4];
  const float* mb2 = (const float*)d_in[5];
  const float* mW3 = (const float*)d_in[6];
  const float* mb3 = (const float*)d_in[7];
  const float* oW1 = (const float*)d_in[8];
  const float* ob1 = (const float*)d_in[9];
  const float* oW2 = (const float*)d_in[10];
  const float* ob2 = (const float*)d_in[11];
  const float* oW3 = (const float*)d_in[12];
  const float* ob3 = (const float*)d_in[13];
  float* out = (float*)d_out;

  // d_out doubles as scratch for h1d (12.8MB f32) + h1s (6.4MB bf16): both are
  // fully consumed by bin_fused before fused_tail overwrites out.
  float* h1d_buf = (float*)d_out;
  short* h1s_buf = (short*)((char*)d_out + (size_t)NP * HID * 4);

  // ws layout (~20.4MB; proven ws >= 33.3MB):
  // wq | gOff | binStart | cntN | pairs | rsum
  char* p = (char*)d_ws;
  short* wqs = (short*)p;            p += (size_t)WQ_FRAGS * 64 * 16;
  int* gOff = (int*)p;               p += (size_t)NBIN * NWG * 4;
  int* binStart = (int*)p;           p += 400 * 4;
  int* cntN = (int*)p;               p += (size_t)NP_PAD * 4;
  unsigned* pairs = (unsigned*)p;    p += (size_t)NE * 4;
  float* rsum = (float*)p;

  setup_kernel<<<NWG + 1 + TILE_BLOCKS, 256, 0, stream>>>(
      x, ei, mW1, mb1, mW2, mW3, oW1, oW2, oW3, gOff, wqs, h1d_buf, h1s_buf);

  scan_bins_kernel<<<1, 512, 0, stream>>>(gOff, binStart);
  bin_scatter_kernel<<<NWG, 256, 0, stream>>>(ei, gOff, pairs);

  bin_fused_kernel<<<NBIN, 512, 0, stream>>>(
      h1s_buf, h1d_buf, wqs, pairs, binStart, mb2, rsum, cntN);

  fused_tail_kernel<<<TILE_BLOCKS, 256, 0, stream>>>(
      x, wqs, rsum, cntN, mb3, ob1, ob2, ob3, out);
}

// Round 19
// 154.760 us; speedup vs baseline: 1.1570x; 1.1570x over previous
//
#include <hip/hip_runtime.h>

#define NP 100000
#define NE 1600000
#define SD 64      // STATE_DIM
#define HID 32
#define MSG 64
#define NP_PAD 100352
#define NTILE (NP / 16)          // 6250
#define TILE_BLOCKS ((NTILE + 3) / 4)     // 1563
#define BINSZ 512
#define NBIN ((NP + BINSZ - 1) / BINSZ)   // 196
#define EPW 8192
#define NWG ((NE + EPW - 1) / EPW)        // 196

typedef float v4f __attribute__((ext_vector_type(4)));
typedef short v4s __attribute__((ext_vector_type(4)));
typedef short v8s __attribute__((ext_vector_type(8)));
typedef __bf16 v8bf __attribute__((ext_vector_type(8)));

// weight-frag ids (each frag = 64 lanes x v8s = 1 KiB):
// edge MLP: 0-3 w1s hi [t*2+kc], 4-7 w1s lo, 8-11 w1d hi [t*2+kc], 12-15 w1d lo,
//           16-17 w2 hi[t], 18-19 w2 lo, 20-23 w3 hi[t], 24-27 w3 lo
// node MLP: 28-35 oW1 hi [t*4+kc], 36-43 oW1 lo, 44-45 oW2 hi, 46-47 oW2 lo,
//           48-51 oW3 hi[t], 52-55 oW3 lo
#define WQ_FRAGS 56

__device__ __forceinline__ v4f MFMA32(v8s a, v8s b, v4f c) {
  return __builtin_amdgcn_mfma_f32_16x16x32_bf16(
      __builtin_bit_cast(v8bf, a), __builtin_bit_cast(v8bf, b), c, 0, 0, 0);
}

__device__ __forceinline__ short f2bf(float f) {   // HW RNE cvt
  return __builtin_bit_cast(short, (__bf16)f);
}
__device__ __forceinline__ float bf2f(short s) {
  unsigned u = ((unsigned)(unsigned short)s) << 16;
  return __builtin_bit_cast(float, u);
}

// 3-term split-bf16 product: C += Ah*Bh + Ah*Bl + Al*Bh (error ~2^-17 rel)
__device__ __forceinline__ v4f mfma3(v8s ah, v8s al, v8s bh, v8s bl, v4f c) {
  c = MFMA32(al, bh, c);
  c = MFMA32(ah, bl, c);
  c = MFMA32(ah, bh, c);
  return c;
}

// A-frag (hi/lo) from row-major W[K][ld]: A[m][k] = W[k][m0+l15]
__device__ __forceinline__ void load_wfrag(const float* __restrict__ W, int ld,
                                           int kb, int m0, int lq, int l15,
                                           v8s* hi, v8s* lo) {
  v8s h, l;
#pragma unroll
  for (int j = 0; j < 8; ++j) {
    int k = kb + ((j < 4) ? (4 * lq + j) : (16 + 4 * lq + (j - 4)));
    float v = W[k * ld + m0 + l15];
    short hb = f2bf(v);
    h[j] = hb;
    l[j] = f2bf(v - bf2f(hb));
  }
  *hi = h;
  *lo = l;
}

// split two v4f halves into one split B-frag (no relu)
__device__ __forceinline__ void split8(v4f a, v4f b, v8s* hi, v8s* lo) {
  v8s h, l;
#pragma unroll
  for (int j = 0; j < 4; ++j) {
    short ha = f2bf(a[j]); h[j] = ha; l[j] = f2bf(a[j] - bf2f(ha));
    short hb = f2bf(b[j]); h[j + 4] = hb; l[j + 4] = f2bf(b[j] - bf2f(hb));
  }
  *hi = h;
  *lo = l;
}

// B-frag (hi/lo) from an f32 feature row
__device__ __forceinline__ void load_xfrag(const float* xs, int kb, int lq,
                                           v8s* hi, v8s* lo) {
  v4f a = *reinterpret_cast<const v4f*>(xs + kb + 4 * lq);
  v4f b = *reinterpret_cast<const v4f*>(xs + kb + 16 + 4 * lq);
  split8(a, b, hi, lo);
}

// D blocks -> next-layer split B-frag with relu
__device__ __forceinline__ void chain_frag(v4f d0, v4f d1, v8s* hi, v8s* lo) {
  v4f a, b;
#pragma unroll
  for (int j = 0; j < 4; ++j) {
    a[j] = fmaxf(d0[j], 0.f);
    b[j] = fmaxf(d1[j], 0.f);
  }
  split8(a, b, hi, lo);
}

// D blocks -> next-layer bf16 B-frag with relu, hi only (per-edge-independent
// quantization error, aggregates as sqrt(cnt))
__device__ __forceinline__ v8s chain_hi(v4f d0, v4f d1) {
  v8s h;
#pragma unroll
  for (int j = 0; j < 4; ++j) {
    h[j] = f2bf(fmaxf(d0[j], 0.f));
    h[j + 4] = f2bf(fmaxf(d1[j], 0.f));
  }
  return h;
}

// ---------------- setup: bin_count (blocks 0..NWG-1) | prew (block NWG) |
//                  prep (blocks NWG+1 ..) -- all independent ----------------
__global__ __launch_bounds__(256, 2) void setup_kernel(
    const float* __restrict__ x, const int* __restrict__ ei,
    const float* __restrict__ mW1, const float* __restrict__ mb1,
    const float* __restrict__ mW2, const float* __restrict__ mW3,
    const float* __restrict__ oW1, const float* __restrict__ oW2,
    const float* __restrict__ oW3,
    int* __restrict__ gOff, short* __restrict__ wqs,
    float* __restrict__ h1d_buf, short* __restrict__ h1s_buf) {
  __shared__ int cnt[NBIN];
  const int blk = blockIdx.x;

  if (blk < NWG) {
    // ---- per-(bin, WG) histogram ----
    for (int i = threadIdx.x; i < NBIN; i += 256) cnt[i] = 0;
    __syncthreads();
    const int e0 = blk * EPW;
    const int e1 = (e0 + EPW < NE) ? e0 + EPW : NE;
    for (int e = e0 + threadIdx.x; e < e1; e += 256)
      atomicAdd(&cnt[ei[NE + e] >> 9], 1);
    __syncthreads();
    for (int i = threadIdx.x; i < NBIN; i += 256) gOff[i * NWG + blk] = cnt[i];
    return;
  }

  const int lane = threadIdx.x & 63;
  const int l15 = lane & 15;
  const int lq = lane >> 4;

  if (blk == NWG) {
    // ---- weight prequantization (64 threads) ----
    if (threadIdx.x >= 64) return;
    v8s* wq = reinterpret_cast<v8s*>(wqs);
    v8s h, l;
#pragma unroll
    for (int t = 0; t < 2; ++t)
#pragma unroll
      for (int kc = 0; kc < 2; ++kc) {
        load_wfrag(mW1, HID, kc * 32, t * 16, lq, l15, &h, &l);
        wq[(t * 2 + kc) * 64 + lane] = h;
        wq[(4 + t * 2 + kc) * 64 + lane] = l;
        load_wfrag(mW1, HID, 64 + kc * 32, t * 16, lq, l15, &h, &l);
        wq[(8 + t * 2 + kc) * 64 + lane] = h;
        wq[(12 + t * 2 + kc) * 64 + lane] = l;
      }
#pragma unroll
    for (int t = 0; t < 2; ++t) {
      load_wfrag(mW2, HID, 0, t * 16, lq, l15, &h, &l);
      wq[(16 + t) * 64 + lane] = h;
      wq[(18 + t) * 64 + lane] = l;
    }
#pragma unroll
    for (int t = 0; t < 4; ++t) {
      load_wfrag(mW3, MSG, 0, t * 16, lq, l15, &h, &l);
      wq[(20 + t) * 64 + lane] = h;
      wq[(24 + t) * 64 + lane] = l;
    }
#pragma unroll
    for (int t = 0; t < 2; ++t)
#pragma unroll
      for (int kc = 0; kc < 4; ++kc) {
        load_wfrag(oW1, HID, kc * 32, t * 16, lq, l15, &h, &l);
        wq[(28 + t * 4 + kc) * 64 + lane] = h;
        wq[(36 + t * 4 + kc) * 64 + lane] = l;
      }
#pragma unroll
    for (int t = 0; t < 2; ++t) {
      load_wfrag(oW2, HID, 0, t * 16, lq, l15, &h, &l);
      wq[(44 + t) * 64 + lane] = h;
      wq[(46 + t) * 64 + lane] = l;
    }
#pragma unroll
    for (int t = 0; t < 4; ++t) {
      load_wfrag(oW3, SD, 0, t * 16, lq, l15, &h, &l);
      wq[(48 + t) * 64 + lane] = h;
      wq[(52 + t) * 64 + lane] = l;
    }
    return;
  }

  // ---- prep: h1d (f32, split-exact) + h1s (bf16) per node, 16 nodes/wave.
  const int tile = ((blk - NWG - 1) * 256 + (int)threadIdx.x) >> 6;
  if (tile >= NTILE) return;
  const int node = tile * 16 + l15;

  v4f d0, d1, s0 = {0.f, 0.f, 0.f, 0.f}, s1 = {0.f, 0.f, 0.f, 0.f};
#pragma unroll
  for (int q = 0; q < 4; ++q) {
    d0[q] = mb1[4 * lq + q];
    d1[q] = mb1[16 + 4 * lq + q];
  }
#pragma unroll
  for (int kc = 0; kc < 2; ++kc) {
    v8s xh, xl, wh, wl;
    load_xfrag(x + (size_t)node * SD, kc * 32, lq, &xh, &xl);
    load_wfrag(mW1, HID, 64 + kc * 32, 0, lq, l15, &wh, &wl);
    d0 = mfma3(wh, wl, xh, xl, d0);
    load_wfrag(mW1, HID, 64 + kc * 32, 16, lq, l15, &wh, &wl);
    d1 = mfma3(wh, wl, xh, xl, d1);
    load_wfrag(mW1, HID, kc * 32, 0, lq, l15, &wh, &wl);
    s0 = mfma3(wh, wl, xh, xl, s0);
    load_wfrag(mW1, HID, kc * 32, 16, lq, l15, &wh, &wl);
    s1 = mfma3(wh, wl, xh, xl, s1);
  }
  *reinterpret_cast<v4f*>(h1d_buf + (size_t)node * HID + 4 * lq) = d0;
  *reinterpret_cast<v4f*>(h1d_buf + (size_t)node * HID + 16 + 4 * lq) = d1;
  v4s q0, q1;
#pragma unroll
  for (int q = 0; q < 4; ++q) {
    q0[q] = f2bf(s0[q]);
    q1[q] = f2bf(s1[q]);
  }
  *reinterpret_cast<v4s*>(h1s_buf + (size_t)node * HID + 4 * lq) = q0;
  *reinterpret_cast<v4s*>(h1s_buf + (size_t)node * HID + 16 + 4 * lq) = q1;
}

// ---------------- CSR build (XCD-exclusive radix) ----------------

// scan: int4-vectorized per-bin prefix + wave-parallel scan of bin totals
__global__ __launch_bounds__(256) void scan_bins_kernel(
    int* __restrict__ gOff, int* __restrict__ binStart) {
  __shared__ int sh[256];
  const int b = threadIdx.x;
  int run = 0;
  if (b < NBIN) {
    int4* row = reinterpret_cast<int4*>(gOff + b * NWG);   // NWG % 4 == 0
#pragma unroll 4
    for (int i = 0; i < NWG / 4; ++i) {
      int4 v = row[i];
      int4 w;
      w.x = run; run += v.x;
      w.y = run; run += v.y;
      w.z = run; run += v.z;
      w.w = run; run += v.w;
      row[i] = w;
    }
  }
  sh[b] = run;   // bin total (0 for b >= NBIN)
  __syncthreads();
  for (int off = 1; off < 256; off <<= 1) {
    int a = (b >= off) ? sh[b - off] : 0;
    __syncthreads();
    sh[b] += a;
    __syncthreads();
  }
  const int excl = sh[b] - run;       // exclusive prefix of bin totals
  if (b <= NBIN) binStart[b] = excl;  // binStart[NBIN] == NE
  if (b < NBIN) {
    int4* row = reinterpret_cast<int4*>(gOff + b * NWG);
#pragma unroll 4
    for (int i = 0; i < NWG / 4; ++i) {
      int4 v = row[i];
      v.x += excl; v.y += excl; v.z += excl; v.w += excl;
      row[i] = v;
    }
  }
}

// scatter packed (src<<9 | dst&511) into bin-grouped array; 26 bits used.
// (bin,WG) regions exclusive -> every sector written by ONE workgroup.
__global__ __launch_bounds__(256) void bin_scatter_kernel(
    const int* __restrict__ ei, const int* __restrict__ gOff,
    unsigned* __restrict__ pairs) {
  __shared__ int cur[NBIN];
  const int w = blockIdx.x;
  for (int i = threadIdx.x; i < NBIN; i += 256) cur[i] = gOff[i * NWG + w];
  __syncthreads();
  const int e0 = w * EPW;
  const int e1 = (e0 + EPW < NE) ? e0 + EPW : NE;
  for (int e = e0 + threadIdx.x; e < e1; e += 256) {
    unsigned s = (unsigned)ei[e];
    unsigned d = (unsigned)ei[NE + e];
    int pos = atomicAdd(&cur[d >> 9], 1);
    pairs[pos] = (s << 9) | (d & (BINSZ - 1));
  }
}

// one WG per bin: per-node hist+scan+scatter entirely in LDS
__global__ __launch_bounds__(512) void bin_csr_kernel(
    const unsigned* __restrict__ pairs, const int* __restrict__ binStart,
    int2* __restrict__ co, int* __restrict__ csr_src) {
  __shared__ int sh[BINSZ];
  __shared__ int cu[BINSZ];
  const int b = blockIdx.x;
  const int t = threadIdx.x;
  cu[t] = 0;
  __syncthreads();
  const int p0 = binStart[b], p1 = binStart[b + 1];
  for (int p = p0 + t; p < p1; p += BINSZ)
    atomicAdd(&cu[pairs[p] & (BINSZ - 1)], 1);
  __syncthreads();
  const int v = cu[t];
  sh[t] = v;
  __syncthreads();
  for (int off = 1; off < BINSZ; off <<= 1) {
    int a = (t >= off) ? sh[t - off] : 0;
    __syncthreads();
    sh[t] += a;
    __syncthreads();
  }
  const int excl = sh[t] - v;
  const int node = b * BINSZ + t;
  if (node < NP) co[node] = make_int2(p0 + excl, v);
  cu[t] = excl;
  __syncthreads();
  for (int p = p0 + t; p < p1; p += BINSZ) {
    unsigned pr = pairs[p];
    int loc = atomicAdd(&cu[pr & (BINSZ - 1)], 1);
    csr_src[p0 + loc] = (int)(pr >> 9);
  }
}

// ---------------- edge loop: TWO nodes per wave (2x memory-level parallelism)
// Adjacent pair (2w, 2w+1): co = one int4; h1d/rsum rows contiguous. Per group
// iteration the two independent co->csr->gather chains cover each other's
// latency; depth-1 overwrite-rotation keeps register pressure < (256,4) cap.
__global__ __launch_bounds__(256, 4) void edge_mfma_kernel(
    const short* __restrict__ h1s, const float* __restrict__ h1d_buf,
    const short* __restrict__ wqs, const int2* __restrict__ co,
    const int* __restrict__ csr_src, const float* __restrict__ mb2,
    float* __restrict__ rsum) {
  const int lane = threadIdx.x & 63;
  const int l15 = lane & 15;
  const int lq = lane >> 4;
  const int wid = (blockIdx.x * 256 + threadIdx.x) >> 6;
  const int nw = gridDim.x * 4;
  const v8s* wq = reinterpret_cast<const v8s*>(wqs);

  const v8s w2h0 = wq[16 * 64 + lane], w2h1 = wq[17 * 64 + lane];
  const v8s w2l0 = wq[18 * 64 + lane], w2l1 = wq[19 * 64 + lane];
  v4f bb0, bb1;
#pragma unroll
  for (int q = 0; q < 4; ++q) {
    bb0[q] = mb2[4 * lq + q];
    bb1[q] = mb2[16 + 4 * lq + q];
  }

  for (int n = wid * 2; n < NP; n += 2 * nw) {   // NP even
    const int4 cc = *reinterpret_cast<const int4*>(co + n);   // co[n], co[n+1]
    const int offA = cc.x, cntA = cc.y;
    const int offB = cc.z, cntB = cc.w;
    const int ngA = (cntA + 15) >> 4;
    const int ngB = (cntB + 15) >> 4;
    const int ngM = ngA > ngB ? ngA : ngB;

    const v4f hA0 = *reinterpret_cast<const v4f*>(h1d_buf + (size_t)n * HID + 4 * lq);
    const v4f hA1 = *reinterpret_cast<const v4f*>(h1d_buf + (size_t)n * HID + 16 + 4 * lq);
    const v4f hB0 = *reinterpret_cast<const v4f*>(h1d_buf + (size_t)(n + 1) * HID + 4 * lq);
    const v4f hB1 = *reinterpret_cast<const v4f*>(h1d_buf + (size_t)(n + 1) * HID + 16 + 4 * lq);

    v4f rA0 = {0.f, 0.f, 0.f, 0.f}, rA1 = {0.f, 0.f, 0.f, 0.f};
    v4f rB0 = {0.f, 0.f, 0.f, 0.f}, rB1 = {0.f, 0.f, 0.f, 0.f};

    // prologue: group-0 indices + gathers for both nodes (two chains in flight)
    int sA = (l15 < cntA) ? csr_src[offA + l15] : 0;
    int sB = (l15 < cntB) ? csr_src[offB + l15] : 0;
    v4s aA = *reinterpret_cast<const v4s*>(h1s + (size_t)sA * HID + 4 * lq);
    v4s bA = *reinterpret_cast<const v4s*>(h1s + (size_t)sA * HID + 16 + 4 * lq);
    v4s aB = *reinterpret_cast<const v4s*>(h1s + (size_t)sB * HID + 4 * lq);
    v4s bB = *reinterpret_cast<const v4s*>(h1s + (size_t)sB * HID + 16 + 4 * lq);

    int remA = cntA, remB = cntB;
    for (int g = 0; g < ngM; ++g) {
      // 1. issue both next-group index loads
      int sAn = (l15 < remA - 16) ? csr_src[offA + (g + 1) * 16 + l15] : 0;
      int sBn = (l15 < remB - 16) ? csr_src[offB + (g + 1) * 16 + l15] : 0;

      // 2. compute A.g (covers sAn's latency)  [wave-uniform guard]
      if (g < ngA) {
        v4f d0, d1;
#pragma unroll
        for (int q = 0; q < 4; ++q) {
          d0[q] = hA0[q] + bf2f(aA[q]);
          d1[q] = hA1[q] + bf2f(bA[q]);
        }
        v8s ph = chain_hi(d0, d1);
        v4f e0 = bb0, e1 = bb1;
        e0 = MFMA32(w2h0, ph, e0);
        e0 = MFMA32(w2l0, ph, e0);
        e1 = MFMA32(w2h1, ph, e1);
        e1 = MFMA32(w2l1, ph, e1);
        if (l15 < remA) {
#pragma unroll
          for (int j = 0; j < 4; ++j) {
            rA0[j] += fmaxf(e0[j], 0.f);
            rA1[j] += fmaxf(e1[j], 0.f);
          }
        }
      }
      // 3. overwrite-gather A's next rows (lands during compute B + next iter)
      aA = *reinterpret_cast<const v4s*>(h1s + (size_t)sAn * HID + 4 * lq);
      bA = *reinterpret_cast<const v4s*>(h1s + (size_t)sAn * HID + 16 + 4 * lq);

      // 4. compute B.g (covers A-gather + sBn latency)
      if (g < ngB) {
        v4f d0, d1;
#pragma unroll
        for (int q = 0; q < 4; ++q) {
          d0[q] = hB0[q] + bf2f(aB[q]);
          d1[q] = hB1[q] + bf2f(bB[q]);
        }
        v8s ph = chain_hi(d0, d1);
        v4f e0 = bb0, e1 = bb1;
        e0 = MFMA32(w2h0, ph, e0);
        e0 = MFMA32(w2l0, ph, e0);
        e1 = MFMA32(w2h1, ph, e1);
        e1 = MFMA32(w2l1, ph, e1);
        if (l15 < remB) {
#pragma unroll
          for (int j = 0; j < 4; ++j) {
            rB0[j] += fmaxf(e0[j], 0.f);
            rB1[j] += fmaxf(e1[j], 0.f);
          }
        }
      }
      // 5. overwrite-gather B's next rows (lands during next iter's compute A)
      aB = *reinterpret_cast<const v4s*>(h1s + (size_t)sBn * HID + 4 * lq);
      bB = *reinterpret_cast<const v4s*>(h1s + (size_t)sBn * HID + 16 + 4 * lq);

      remA -= 16;
      remB -= 16;
    }

    // reduce relu-sums over the 16 slot-columns; write adjacent rsum rows
#pragma unroll
    for (int j = 0; j < 4; ++j) {
      float a = rA0[j], b = rA1[j], c = rB0[j], d = rB1[j];
      a += __shfl_xor(a, 1); a += __shfl_xor(a, 2);
      a += __shfl_xor(a, 4); a += __shfl_xor(a, 8);
      b += __shfl_xor(b, 1); b += __shfl_xor(b, 2);
      b += __shfl_xor(b, 4); b += __shfl_xor(b, 8);
      c += __shfl_xor(c, 1); c += __shfl_xor(c, 2);
      c += __shfl_xor(c, 4); c += __shfl_xor(c, 8);
      d += __shfl_xor(d, 1); d += __shfl_xor(d, 2);
      d += __shfl_xor(d, 4); d += __shfl_xor(d, 8);
      rA0[j] = a; rA1[j] = b; rB0[j] = c; rB1[j] = d;
    }
    if (l15 == 0) {
      *reinterpret_cast<v4f*>(rsum + (size_t)n * HID + 4 * lq) = rA0;
      *reinterpret_cast<v4f*>(rsum + (size_t)n * HID + 16 + 4 * lq) = rA1;
      *reinterpret_cast<v4f*>(rsum + (size_t)(n + 1) * HID + 4 * lq) = rB0;
      *reinterpret_cast<v4f*>(rsum + (size_t)(n + 1) * HID + 16 + 4 * lq) = rB1;
    }
  }
}

// ---------------- fused tail: edge layer3 + full node MLP, 16 nodes/wave ----
__global__ __launch_bounds__(256, 2) void fused_tail_kernel(
    const float* __restrict__ x, const short* __restrict__ wqs,
    const float* __restrict__ rsum, const int2* __restrict__ co,
    const float* __restrict__ mb3,
    const float* __restrict__ ob1, const float* __restrict__ ob2,
    const float* __restrict__ ob3,
    float* __restrict__ out) {
  const int lane = threadIdx.x & 63;
  const int l15 = lane & 15;
  const int lq = lane >> 4;
  const int tile = (blockIdx.x * 256 + threadIdx.x) >> 6;
  if (tile >= NTILE) return;
  const v8s* wq = reinterpret_cast<const v8s*>(wqs);

  const int node = tile * 16 + l15;
  const float fc = (float)co[node].y;

  // edge layer 3: msg = mW3^T r + fc*mb3
  v4f ra = *reinterpret_cast<const v4f*>(rsum + (size_t)node * HID + 4 * lq);
  v4f rb = *reinterpret_cast<const v4f*>(rsum + (size_t)node * HID + 16 + 4 * lq);
  v8s bh, bl;
  split8(ra, rb, &bh, &bl);

  v4f m[4];
#pragma unroll
  for (int t = 0; t < 4; ++t) {
    v4f c = {0.f, 0.f, 0.f, 0.f};
    c = mfma3(wq[(20 + t) * 64 + lane], wq[(24 + t) * 64 + lane], bh, bl, c);
#pragma unroll
    for (int q = 0; q < 4; ++q) c[q] += fc * mb3[t * 16 + 4 * lq + q];
    m[t] = c;
  }

  // node layer 1 on [x || msg]
  v4f d0, d1;
#pragma unroll
  for (int q = 0; q < 4; ++q) {
    d0[q] = ob1[4 * lq + q];
    d1[q] = ob1[16 + 4 * lq + q];
  }
#pragma unroll
  for (int kc = 0; kc < 2; ++kc) {
    v8s xh, xl;
    load_xfrag(x + (size_t)node * SD, kc * 32, lq, &xh, &xl);
    d0 = mfma3(wq[(28 + kc) * 64 + lane], wq[(36 + kc) * 64 + lane], xh, xl, d0);
    d1 = mfma3(wq[(32 + kc) * 64 + lane], wq[(40 + kc) * 64 + lane], xh, xl, d1);
  }
#pragma unroll
  for (int kc = 0; kc < 2; ++kc) {
    v8s mh, ml;
    split8(m[kc * 2], m[kc * 2 + 1], &mh, &ml);
    d0 = mfma3(wq[(30 + kc) * 64 + lane], wq[(38 + kc) * 64 + lane], mh, ml, d0);
    d1 = mfma3(wq[(34 + kc) * 64 + lane], wq[(42 + kc) * 64 + lane], mh, ml, d1);
  }

  // node layer 2
  v8s ph, pl;
  chain_frag(d0, d1, &ph, &pl);
  v4f e0, e1;
#pragma unroll
  for (int q = 0; q < 4; ++q) {
    e0[q] = ob2[4 * lq + q];
    e1[q] = ob2[16 + 4 * lq + q];
  }
  e0 = mfma3(wq[44 * 64 + lane], wq[46 * 64 + lane], ph, pl, e0);
  e1 = mfma3(wq[45 * 64 + lane], wq[47 * 64 + lane], ph, pl, e1);

  // node layer 3 -> out
  v8s rh, rl;
  chain_frag(e0, e1, &rh, &rl);
  float* orow = out + (size_t)node * SD;
#pragma unroll
  for (int t = 0; t < 4; ++t) {
    v4f c;
#pragma unroll
    for (int q = 0; q < 4; ++q) c[q] = ob3[t * 16 + 4 * lq + q];
    c = mfma3(wq[(48 + t) * 64 + lane], wq[(52 + t) * 64 + lane], rh, rl, c);
    *reinterpret_cast<v4f*>(orow + t * 16 + 4 * lq) = c;
  }
}

extern "C" void kernel_launch(void* const* d_in, const int* in_sizes, int n_in,
                              void* d_out, int out_size, void* d_ws,
                              size_t ws_size, hipStream_t stream) {
  const float* x = (const float*)d_in[0];
  const int* ei = (const int*)d_in[1];
  const float* mW1 = (const float*)d_in[2];
  const float* mb1 = (const float*)d_in[3];
  const float* mW2 = (const float*)d_in[4];
  const float* mb2 = (const float*)d_in[5];
  const float* mW3 = (const float*)d_in[6];
  const float* mb3 = (const float*)d_in[7];
  const float* oW1 = (const float*)d_in[8];
  const float* ob1 = (const float*)d_in[9];
  const float* oW2 = (const float*)d_in[10];
  const float* ob2 = (const float*)d_in[11];
  const float* oW3 = (const float*)d_in[12];
  const float* ob3 = (const float*)d_in[13];
  float* out = (float*)d_out;

  // d_out doubles as scratch for h1d (12.8MB f32) + h1s (6.4MB bf16): both are
  // fully consumed by edge_mfma before fused_tail overwrites out.
  float* h1d_buf = (float*)d_out;
  short* h1s_buf = (short*)((char*)d_out + (size_t)NP * HID * 4);

  // ws layout (~20.6MB; proven ws >= 33.3MB):
  // wq | gOff | binStart | co | csr_src | pairs/rsum (rsum aliases pairs)
  char* p = (char*)d_ws;
  short* wqs = (short*)p;            p += (size_t)WQ_FRAGS * 64 * 16;
  int* gOff = (int*)p;               p += (size_t)NBIN * NWG * 4;
  int* binStart = (int*)p;           p += 200 * 4;
  int2* co = (int2*)p;               p += (size_t)NP_PAD * 8;
  int* csr_src = (int*)p;            p += (size_t)NE * 4;
  unsigned* pairs = (unsigned*)p;
  float* rsum = (float*)p;           // aliases pairs (dead after bin_csr)

  setup_kernel<<<NWG + 1 + TILE_BLOCKS, 256, 0, stream>>>(
      x, ei, mW1, mb1, mW2, mW3, oW1, oW2, oW3, gOff, wqs, h1d_buf, h1s_buf);

  scan_bins_kernel<<<1, 256, 0, stream>>>(gOff, binStart);
  bin_scatter_kernel<<<NWG, 256, 0, stream>>>(ei, gOff, pairs);
  bin_csr_kernel<<<NBIN, 512, 0, stream>>>(pairs, binStart, co, csr_src);

  edge_mfma_kernel<<<2048, 256, 0, stream>>>(
      h1s_buf, h1d_buf, wqs, co, csr_src, mb2, rsum);

  fused_tail_kernel<<<TILE_BLOCKS, 256, 0, stream>>>(
      x, wqs, rsum, co, mb3, ob1, ob2, ob3, out);
}

// Round 22
// 147.781 us; speedup vs baseline: 1.2116x; 1.0472x over previous
//
#include <hip/hip_runtime.h>

#define NP 100000
#define NE 1600000
#define SD 64      // STATE_DIM
#define HID 32
#define MSG 64
#define NP_PAD 100352
#define NTILE (NP / 16)          // 6250
#define TILE_BLOCKS ((NTILE + 3) / 4)     // 1563
#define BINSZ 512
#define NBIN ((NP + BINSZ - 1) / BINSZ)   // 196
#define EPW 8192
#define NWG ((NE + EPW - 1) / EPW)        // 196

typedef float v4f __attribute__((ext_vector_type(4)));
typedef short v4s __attribute__((ext_vector_type(4)));
typedef short v8s __attribute__((ext_vector_type(8)));
typedef __bf16 v8bf __attribute__((ext_vector_type(8)));

// weight-frag ids (each frag = 64 lanes x v8s = 1 KiB):
// edge MLP: 0-3 w1s hi [t*2+kc], 4-7 w1s lo, 8-11 w1d hi [t*2+kc], 12-15 w1d lo,
//           16-17 w2 hi[t], 18-19 w2 lo, 20-23 w3 hi[t], 24-27 w3 lo
// node MLP: 28-35 oW1 hi [t*4+kc], 36-43 oW1 lo, 44-45 oW2 hi, 46-47 oW2 lo,
//           48-51 oW3 hi[t], 52-55 oW3 lo
#define WQ_FRAGS 56

__device__ __forceinline__ v4f MFMA32(v8s a, v8s b, v4f c) {
  return __builtin_amdgcn_mfma_f32_16x16x32_bf16(
      __builtin_bit_cast(v8bf, a), __builtin_bit_cast(v8bf, b), c, 0, 0, 0);
}

__device__ __forceinline__ short f2bf(float f) {   // HW RNE cvt
  return __builtin_bit_cast(short, (__bf16)f);
}
__device__ __forceinline__ float bf2f(short s) {
  unsigned u = ((unsigned)(unsigned short)s) << 16;
  return __builtin_bit_cast(float, u);
}

// 3-term split-bf16 product: C += Ah*Bh + Ah*Bl + Al*Bh (error ~2^-17 rel)
__device__ __forceinline__ v4f mfma3(v8s ah, v8s al, v8s bh, v8s bl, v4f c) {
  c = MFMA32(al, bh, c);
  c = MFMA32(ah, bl, c);
  c = MFMA32(ah, bh, c);
  return c;
}

// A-frag (hi/lo) from row-major W[K][ld]: A[m][k] = W[k][m0+l15]
__device__ __forceinline__ void load_wfrag(const float* __restrict__ W, int ld,
                                           int kb, int m0, int lq, int l15,
                                           v8s* hi, v8s* lo) {
  v8s h, l;
#pragma unroll
  for (int j = 0; j < 8; ++j) {
    int k = kb + ((j < 4) ? (4 * lq + j) : (16 + 4 * lq + (j - 4)));
    float v = W[k * ld + m0 + l15];
    short hb = f2bf(v);
    h[j] = hb;
    l[j] = f2bf(v - bf2f(hb));
  }
  *hi = h;
  *lo = l;
}

// split two v4f halves into one split B-frag (no relu)
__device__ __forceinline__ void split8(v4f a, v4f b, v8s* hi, v8s* lo) {
  v8s h, l;
#pragma unroll
  for (int j = 0; j < 4; ++j) {
    short ha = f2bf(a[j]); h[j] = ha; l[j] = f2bf(a[j] - bf2f(ha));
    short hb = f2bf(b[j]); h[j + 4] = hb; l[j + 4] = f2bf(b[j] - bf2f(hb));
  }
  *hi = h;
  *lo = l;
}

// B-frag (hi/lo) from an f32 feature row
__device__ __forceinline__ void load_xfrag(const float* xs, int kb, int lq,
                                           v8s* hi, v8s* lo) {
  v4f a = *reinterpret_cast<const v4f*>(xs + kb + 4 * lq);
  v4f b = *reinterpret_cast<const v4f*>(xs + kb + 16 + 4 * lq);
  split8(a, b, hi, lo);
}

// D blocks -> next-layer split B-frag with relu
__device__ __forceinline__ void chain_frag(v4f d0, v4f d1, v8s* hi, v8s* lo) {
  v4f a, b;
#pragma unroll
  for (int j = 0; j < 4; ++j) {
    a[j] = fmaxf(d0[j], 0.f);
    b[j] = fmaxf(d1[j], 0.f);
  }
  split8(a, b, hi, lo);
}

// D blocks -> next-layer bf16 B-frag with relu, hi only (per-edge-independent
// quantization error, aggregates as sqrt(cnt))
__device__ __forceinline__ v8s chain_hi(v4f d0, v4f d1) {
  v8s h;
#pragma unroll
  for (int j = 0; j < 4; ++j) {
    h[j] = f2bf(fmaxf(d0[j], 0.f));
    h[j + 4] = f2bf(fmaxf(d1[j], 0.f));
  }
  return h;
}

// ---------------- setup: bin_count (blocks 0..NWG-1) | prew (block NWG) |
//                  prep (blocks NWG+1 ..) -- all independent ----------------
__global__ __launch_bounds__(256, 2) void setup_kernel(
    const float* __restrict__ x, const int* __restrict__ ei,
    const float* __restrict__ mW1, const float* __restrict__ mb1,
    const float* __restrict__ mW2, const float* __restrict__ mW3,
    const float* __restrict__ oW1, const float* __restrict__ oW2,
    const float* __restrict__ oW3,
    int* __restrict__ gOff, short* __restrict__ wqs,
    float* __restrict__ h1d_buf, short* __restrict__ h1s_buf) {
  __shared__ int cnt[NBIN];
  const int blk = blockIdx.x;

  if (blk < NWG) {
    // ---- per-(bin, WG) histogram; int4 loads with exact tail guard.
    //      NE % 4 == 0, so the last WG's 2560 edges are whole int4s. ----
    for (int i = threadIdx.x; i < NBIN; i += 256) cnt[i] = 0;
    __syncthreads();
    const int e0 = blk * EPW;
    const int rem = (NE - e0 < EPW) ? (NE - e0) : EPW;
    const int n4 = rem >> 2;           // valid int4 count for this WG
    const int4* d4 = reinterpret_cast<const int4*>(ei + NE + e0);
    for (int j = threadIdx.x; j < n4; j += 256) {
      int4 a = d4[j];
      atomicAdd(&cnt[a.x >> 9], 1);
      atomicAdd(&cnt[a.y >> 9], 1);
      atomicAdd(&cnt[a.z >> 9], 1);
      atomicAdd(&cnt[a.w >> 9], 1);
    }
    __syncthreads();
    for (int i = threadIdx.x; i < NBIN; i += 256) gOff[i * NWG + blk] = cnt[i];
    return;
  }

  const int lane = threadIdx.x & 63;
  const int l15 = lane & 15;
  const int lq = lane >> 4;

  if (blk == NWG) {
    // ---- weight prequantization (64 threads) ----
    if (threadIdx.x >= 64) return;
    v8s* wq = reinterpret_cast<v8s*>(wqs);
    v8s h, l;
#pragma unroll
    for (int t = 0; t < 2; ++t)
#pragma unroll
      for (int kc = 0; kc < 2; ++kc) {
        load_wfrag(mW1, HID, kc * 32, t * 16, lq, l15, &h, &l);
        wq[(t * 2 + kc) * 64 + lane] = h;
        wq[(4 + t * 2 + kc) * 64 + lane] = l;
        load_wfrag(mW1, HID, 64 + kc * 32, t * 16, lq, l15, &h, &l);
        wq[(8 + t * 2 + kc) * 64 + lane] = h;
        wq[(12 + t * 2 + kc) * 64 + lane] = l;
      }
#pragma unroll
    for (int t = 0; t < 2; ++t) {
      load_wfrag(mW2, HID, 0, t * 16, lq, l15, &h, &l);
      wq[(16 + t) * 64 + lane] = h;
      wq[(18 + t) * 64 + lane] = l;
    }
#pragma unroll
    for (int t = 0; t < 4; ++t) {
      load_wfrag(mW3, MSG, 0, t * 16, lq, l15, &h, &l);
      wq[(20 + t) * 64 + lane] = h;
      wq[(24 + t) * 64 + lane] = l;
    }
#pragma unroll
    for (int t = 0; t < 2; ++t)
#pragma unroll
      for (int kc = 0; kc < 4; ++kc) {
        load_wfrag(oW1, HID, kc * 32, t * 16, lq, l15, &h, &l);
        wq[(28 + t * 4 + kc) * 64 + lane] = h;
        wq[(36 + t * 4 + kc) * 64 + lane] = l;
      }
#pragma unroll
    for (int t = 0; t < 2; ++t) {
      load_wfrag(oW2, HID, 0, t * 16, lq, l15, &h, &l);
      wq[(44 + t) * 64 + lane] = h;
      wq[(46 + t) * 64 + lane] = l;
    }
#pragma unroll
    for (int t = 0; t < 4; ++t) {
      load_wfrag(oW3, SD, 0, t * 16, lq, l15, &h, &l);
      wq[(48 + t) * 64 + lane] = h;
      wq[(52 + t) * 64 + lane] = l;
    }
    return;
  }

  // ---- prep: h1d (f32, split-exact) + h1s (bf16) per node, 16 nodes/wave.
  const int tile = ((blk - NWG - 1) * 256 + (int)threadIdx.x) >> 6;
  if (tile >= NTILE) return;
  const int node = tile * 16 + l15;

  v4f d0, d1, s0 = {0.f, 0.f, 0.f, 0.f}, s1 = {0.f, 0.f, 0.f, 0.f};
#pragma unroll
  for (int q = 0; q < 4; ++q) {
    d0[q] = mb1[4 * lq + q];
    d1[q] = mb1[16 + 4 * lq + q];
  }
#pragma unroll
  for (int kc = 0; kc < 2; ++kc) {
    v8s xh, xl, wh, wl;
    load_xfrag(x + (size_t)node * SD, kc * 32, lq, &xh, &xl);
    load_wfrag(mW1, HID, 64 + kc * 32, 0, lq, l15, &wh, &wl);
    d0 = mfma3(wh, wl, xh, xl, d0);
    load_wfrag(mW1, HID, 64 + kc * 32, 16, lq, l15, &wh, &wl);
    d1 = mfma3(wh, wl, xh, xl, d1);
    load_wfrag(mW1, HID, kc * 32, 0, lq, l15, &wh, &wl);
    s0 = mfma3(wh, wl, xh, xl, s0);
    load_wfrag(mW1, HID, kc * 32, 16, lq, l15, &wh, &wl);
    s1 = mfma3(wh, wl, xh, xl, s1);
  }
  *reinterpret_cast<v4f*>(h1d_buf + (size_t)node * HID + 4 * lq) = d0;
  *reinterpret_cast<v4f*>(h1d_buf + (size_t)node * HID + 16 + 4 * lq) = d1;
  v4s q0, q1;
#pragma unroll
  for (int q = 0; q < 4; ++q) {
    q0[q] = f2bf(s0[q]);
    q1[q] = f2bf(s1[q]);
  }
  *reinterpret_cast<v4s*>(h1s_buf + (size_t)node * HID + 4 * lq) = q0;
  *reinterpret_cast<v4s*>(h1s_buf + (size_t)node * HID + 16 + 4 * lq) = q1;
}

// ---------------- CSR build (XCD-exclusive radix) ----------------

// scan: int4-vectorized per-bin prefix + wave-parallel scan of bin totals
__global__ __launch_bounds__(256) void scan_bins_kernel(
    int* __restrict__ gOff, int* __restrict__ binStart) {
  __shared__ int sh[256];
  const int b = threadIdx.x;
  int run = 0;
  if (b < NBIN) {
    int4* row = reinterpret_cast<int4*>(gOff + b * NWG);   // NWG % 4 == 0
#pragma unroll 4
    for (int i = 0; i < NWG / 4; ++i) {
      int4 v = row[i];
      int4 w;
      w.x = run; run += v.x;
      w.y = run; run += v.y;
      w.z = run; run += v.z;
      w.w = run; run += v.w;
      row[i] = w;
    }
  }
  sh[b] = run;   // bin total (0 for b >= NBIN)
  __syncthreads();
  for (int off = 1; off < 256; off <<= 1) {
    int a = (b >= off) ? sh[b - off] : 0;
    __syncthreads();
    sh[b] += a;
    __syncthreads();
  }
  const int excl = sh[b] - run;       // exclusive prefix of bin totals
  if (b <= NBIN) binStart[b] = excl;  // binStart[NBIN] == NE
  if (b < NBIN) {
    int4* row = reinterpret_cast<int4*>(gOff + b * NWG);
#pragma unroll 4
    for (int i = 0; i < NWG / 4; ++i) {
      int4 v = row[i];
      v.x += excl; v.y += excl; v.z += excl; v.w += excl;
      row[i] = v;
    }
  }
}

// scatter packed (src<<9 | dst&511) into bin-grouped array; 26 bits used.
// (bin,WG) regions exclusive -> every sector written by ONE workgroup.
// int4 loads with the same exact tail guard as bin_count.
__global__ __launch_bounds__(256) void bin_scatter_kernel(
    const int* __restrict__ ei, const int* __restrict__ gOff,
    unsigned* __restrict__ pairs) {
  __shared__ int cur[NBIN];
  const int w = blockIdx.x;
  for (int i = threadIdx.x; i < NBIN; i += 256) cur[i] = gOff[i * NWG + w];
  __syncthreads();
  const int e0 = w * EPW;
  const int rem = (NE - e0 < EPW) ? (NE - e0) : EPW;
  const int n4 = rem >> 2;             // valid int4 count (NE % 4 == 0)
  const int4* s4 = reinterpret_cast<const int4*>(ei + e0);
  const int4* d4 = reinterpret_cast<const int4*>(ei + NE + e0);
  for (int j = threadIdx.x; j < n4; j += 256) {
    int4 s = s4[j];
    int4 d = d4[j];
    int p0 = atomicAdd(&cur[d.x >> 9], 1);
    pairs[p0] = ((unsigned)s.x << 9) | ((unsigned)d.x & (BINSZ - 1));
    int p1 = atomicAdd(&cur[d.y >> 9], 1);
    pairs[p1] = ((unsigned)s.y << 9) | ((unsigned)d.y & (BINSZ - 1));
    int p2 = atomicAdd(&cur[d.z >> 9], 1);
    pairs[p2] = ((unsigned)s.z << 9) | ((unsigned)d.z & (BINSZ - 1));
    int p3 = atomicAdd(&cur[d.w >> 9], 1);
    pairs[p3] = ((unsigned)s.w << 9) | ((unsigned)d.w & (BINSZ - 1));
  }
}

// one WG per bin: per-node hist+scan+scatter entirely in LDS
__global__ __launch_bounds__(512) void bin_csr_kernel(
    const unsigned* __restrict__ pairs, const int* __restrict__ binStart,
    int2* __restrict__ co, int* __restrict__ csr_src) {
  __shared__ int sh[BINSZ];
  __shared__ int cu[BINSZ];
  const int b = blockIdx.x;
  const int t = threadIdx.x;
  cu[t] = 0;
  __syncthreads();
  const int p0 = binStart[b], p1 = binStart[b + 1];
  for (int p = p0 + t; p < p1; p += BINSZ)
    atomicAdd(&cu[pairs[p] & (BINSZ - 1)], 1);
  __syncthreads();
  const int v = cu[t];
  sh[t] = v;
  __syncthreads();
  for (int off = 1; off < BINSZ; off <<= 1) {
    int a = (t >= off) ? sh[t - off] : 0;
    __syncthreads();
    sh[t] += a;
    __syncthreads();
  }
  const int excl = sh[t] - v;
  const int node = b * BINSZ + t;
  if (node < NP) co[node] = make_int2(p0 + excl, v);
  cu[t] = excl;
  __syncthreads();
  for (int p = p0 + t; p < p1; p += BINSZ) {
    unsigned pr = pairs[p];
    int loc = atomicAdd(&cu[pr & (BINSZ - 1)], 1);
    csr_src[p0 + loc] = (int)(pr >> 9);
  }
}

// ---------------- edge loop: TWO nodes per wave (2x memory-level parallelism)
// Adjacent pair (2w, 2w+1): co = one int4; h1d/rsum rows contiguous. Per group
// iteration the two independent co->csr->gather chains cover each other's
// latency; depth-1 overwrite-rotation keeps register pressure < (256,4) cap.
__global__ __launch_bounds__(256, 4) void edge_mfma_kernel(
    const short* __restrict__ h1s, const float* __restrict__ h1d_buf,
    const short* __restrict__ wqs, const int2* __restrict__ co,
    const int* __restrict__ csr_src, const float* __restrict__ mb2,
    float* __restrict__ rsum) {
  const int lane = threadIdx.x & 63;
  const int l15 = lane & 15;
  const int lq = lane >> 4;
  const int wid = (blockIdx.x * 256 + threadIdx.x) >> 6;
  const int nw = gridDim.x * 4;
  const v8s* wq = reinterpret_cast<const v8s*>(wqs);

  const v8s w2h0 = wq[16 * 64 + lane], w2h1 = wq[17 * 64 + lane];
  const v8s w2l0 = wq[18 * 64 + lane], w2l1 = wq[19 * 64 + lane];
  v4f bb0, bb1;
#pragma unroll
  for (int q = 0; q < 4; ++q) {
    bb0[q] = mb2[4 * lq + q];
    bb1[q] = mb2[16 + 4 * lq + q];
  }

  for (int n = wid * 2; n < NP; n += 2 * nw) {   // NP even
    const int4 cc = *reinterpret_cast<const int4*>(co + n);   // co[n], co[n+1]
    const int offA = cc.x, cntA = cc.y;
    const int offB = cc.z, cntB = cc.w;
    const int ngA = (cntA + 15) >> 4;
    const int ngB = (cntB + 15) >> 4;
    const int ngM = ngA > ngB ? ngA : ngB;

    const v4f hA0 = *reinterpret_cast<const v4f*>(h1d_buf + (size_t)n * HID + 4 * lq);
    const v4f hA1 = *reinterpret_cast<const v4f*>(h1d_buf + (size_t)n * HID + 16 + 4 * lq);
    const v4f hB0 = *reinterpret_cast<const v4f*>(h1d_buf + (size_t)(n + 1) * HID + 4 * lq);
    const v4f hB1 = *reinterpret_cast<const v4f*>(h1d_buf + (size_t)(n + 1) * HID + 16 + 4 * lq);

    v4f rA0 = {0.f, 0.f, 0.f, 0.f}, rA1 = {0.f, 0.f, 0.f, 0.f};
    v4f rB0 = {0.f, 0.f, 0.f, 0.f}, rB1 = {0.f, 0.f, 0.f, 0.f};

    // prologue: group-0 indices + gathers for both nodes (two chains in flight)
    int sA = (l15 < cntA) ? csr_src[offA + l15] : 0;
    int sB = (l15 < cntB) ? csr_src[offB + l15] : 0;
    v4s aA = *reinterpret_cast<const v4s*>(h1s + (size_t)sA * HID + 4 * lq);
    v4s bA = *reinterpret_cast<const v4s*>(h1s + (size_t)sA * HID + 16 + 4 * lq);
    v4s aB = *reinterpret_cast<const v4s*>(h1s + (size_t)sB * HID + 4 * lq);
    v4s bB = *reinterpret_cast<const v4s*>(h1s + (size_t)sB * HID + 16 + 4 * lq);

    int remA = cntA, remB = cntB;
    for (int g = 0; g < ngM; ++g) {
      // 1. issue both next-group index loads
      int sAn = (l15 < remA - 16) ? csr_src[offA + (g + 1) * 16 + l15] : 0;
      int sBn = (l15 < remB - 16) ? csr_src[offB + (g + 1) * 16 + l15] : 0;

      // 2. compute A.g (covers sAn's latency)  [wave-uniform guard]
      if (g < ngA) {
        v4f d0, d1;
#pragma unroll
        for (int q = 0; q < 4; ++q) {
          d0[q] = hA0[q] + bf2f(aA[q]);
          d1[q] = hA1[q] + bf2f(bA[q]);
        }
        v8s ph = chain_hi(d0, d1);
        v4f e0 = bb0, e1 = bb1;
        e0 = MFMA32(w2h0, ph, e0);
        e0 = MFMA32(w2l0, ph, e0);
        e1 = MFMA32(w2h1, ph, e1);
        e1 = MFMA32(w2l1, ph, e1);
        if (l15 < remA) {
#pragma unroll
          for (int j = 0; j < 4; ++j) {
            rA0[j] += fmaxf(e0[j], 0.f);
            rA1[j] += fmaxf(e1[j], 0.f);
          }
        }
      }
      // 3. overwrite-gather A's next rows (lands during compute B + next iter)
      aA = *reinterpret_cast<const v4s*>(h1s + (size_t)sAn * HID + 4 * lq);
      bA = *reinterpret_cast<const v4s*>(h1s + (size_t)sAn * HID + 16 + 4 * lq);

      // 4. compute B.g (covers A-gather + sBn latency)
      if (g < ngB) {
        v4f d0, d1;
#pragma unroll
        for (int q = 0; q < 4; ++q) {
          d0[q] = hB0[q] + bf2f(aB[q]);
          d1[q] = hB1[q] + bf2f(bB[q]);
        }
        v8s ph = chain_hi(d0, d1);
        v4f e0 = bb0, e1 = bb1;
        e0 = MFMA32(w2h0, ph, e0);
        e0 = MFMA32(w2l0, ph, e0);
        e1 = MFMA32(w2h1, ph, e1);
        e1 = MFMA32(w2l1, ph, e1);
        if (l15 < remB) {
#pragma unroll
          for (int j = 0; j < 4; ++j) {
            rB0[j] += fmaxf(e0[j], 0.f);
            rB1[j] += fmaxf(e1[j], 0.f);
          }
        }
      }
      // 5. overwrite-gather B's next rows (lands during next iter's compute A)
      aB = *reinterpret_cast<const v4s*>(h1s + (size_t)sBn * HID + 4 * lq);
      bB = *reinterpret_cast<const v4s*>(h1s + (size_t)sBn * HID + 16 + 4 * lq);

      remA -= 16;
      remB -= 16;
    }

    // reduce relu-sums over the 16 slot-columns; write adjacent rsum rows
#pragma unroll
    for (int j = 0; j < 4; ++j) {
      float a = rA0[j], b = rA1[j], c = rB0[j], d = rB1[j];
      a += __shfl_xor(a, 1); a += __shfl_xor(a, 2);
      a += __shfl_xor(a, 4); a += __shfl_xor(a, 8);
      b += __shfl_xor(b, 1); b += __shfl_xor(b, 2);
      b += __shfl_xor(b, 4); b += __shfl_xor(b, 8);
      c += __shfl_xor(c, 1); c += __shfl_xor(c, 2);
      c += __shfl_xor(c, 4); c += __shfl_xor(c, 8);
      d += __shfl_xor(d, 1); d += __shfl_xor(d, 2);
      d += __shfl_xor(d, 4); d += __shfl_xor(d, 8);
      rA0[j] = a; rA1[j] = b; rB0[j] = c; rB1[j] = d;
    }
    if (l15 == 0) {
      *reinterpret_cast<v4f*>(rsum + (size_t)n * HID + 4 * lq) = rA0;
      *reinterpret_cast<v4f*>(rsum + (size_t)n * HID + 16 + 4 * lq) = rA1;
      *reinterpret_cast<v4f*>(rsum + (size_t)(n + 1) * HID + 4 * lq) = rB0;
      *reinterpret_cast<v4f*>(rsum + (size_t)(n + 1) * HID + 16 + 4 * lq) = rB1;
    }
  }
}

// ---------------- fused tail: edge layer3 + full node MLP, 16 nodes/wave ----
__global__ __launch_bounds__(256, 2) void fused_tail_kernel(
    const float* __restrict__ x, const short* __restrict__ wqs,
    const float* __restrict__ rsum, const int2* __restrict__ co,
    const float* __restrict__ mb3,
    const float* __restrict__ ob1, const float* __restrict__ ob2,
    const float* __restrict__ ob3,
    float* __restrict__ out) {
  const int lane = threadIdx.x & 63;
  const int l15 = lane & 15;
  const int lq = lane >> 4;
  const int tile = (blockIdx.x * 256 + threadIdx.x) >> 6;
  if (tile >= NTILE) return;
  const v8s* wq = reinterpret_cast<const v8s*>(wqs);

  const int node = tile * 16 + l15;
  const float fc = (float)co[node].y;

  // edge layer 3: msg = mW3^T r + fc*mb3
  v4f ra = *reinterpret_cast<const v4f*>(rsum + (size_t)node * HID + 4 * lq);
  v4f rb = *reinterpret_cast<const v4f*>(rsum + (size_t)node * HID + 16 + 4 * lq);
  v8s bh, bl;
  split8(ra, rb, &bh, &bl);

  v4f m[4];
#pragma unroll
  for (int t = 0; t < 4; ++t) {
    v4f c = {0.f, 0.f, 0.f, 0.f};
    c = mfma3(wq[(20 + t) * 64 + lane], wq[(24 + t) * 64 + lane], bh, bl, c);
#pragma unroll
    for (int q = 0; q < 4; ++q) c[q] += fc * mb3[t * 16 + 4 * lq + q];
    m[t] = c;
  }

  // node layer 1 on [x || msg]
  v4f d0, d1;
#pragma unroll
  for (int q = 0; q < 4; ++q) {
    d0[q] = ob1[4 * lq + q];
    d1[q] = ob1[16 + 4 * lq + q];
  }
#pragma unroll
  for (int kc = 0; kc < 2; ++kc) {
    v8s xh, xl;
    load_xfrag(x + (size_t)node * SD, kc * 32, lq, &xh, &xl);
    d0 = mfma3(wq[(28 + kc) * 64 + lane], wq[(36 + kc) * 64 + lane], xh, xl, d0);
    d1 = mfma3(wq[(32 + kc) * 64 + lane], wq[(40 + kc) * 64 + lane], xh, xl, d1);
  }
#pragma unroll
  for (int kc = 0; kc < 2; ++kc) {
    v8s mh, ml;
    split8(m[kc * 2], m[kc * 2 + 1], &mh, &ml);
    d0 = mfma3(wq[(30 + kc) * 64 + lane], wq[(38 + kc) * 64 + lane], mh, ml, d0);
    d1 = mfma3(wq[(34 + kc) * 64 + lane], wq[(42 + kc) * 64 + lane], mh, ml, d1);
  }

  // node layer 2
  v8s ph, pl;
  chain_frag(d0, d1, &ph, &pl);
  v4f e0, e1;
#pragma unroll
  for (int q = 0; q < 4; ++q) {
    e0[q] = ob2[4 * lq + q];
    e1[q] = ob2[16 + 4 * lq + q];
  }
  e0 = mfma3(wq[44 * 64 + lane], wq[46 * 64 + lane], ph, pl, e0);
  e1 = mfma3(wq[45 * 64 + lane], wq[47 * 64 + lane], ph, pl, e1);

  // node layer 3 -> out
  v8s rh, rl;
  chain_frag(e0, e1, &rh, &rl);
  float* orow = out + (size_t)node * SD;
#pragma unroll
  for (int t = 0; t < 4; ++t) {
    v4f c;
#pragma unroll
    for (int q = 0; q < 4; ++q) c[q] = ob3[t * 16 + 4 * lq + q];
    c = mfma3(wq[(48 + t) * 64 + lane], wq[(52 + t) * 64 + lane], rh, rl, c);
    *reinterpret_cast<v4f*>(orow + t * 16 + 4 * lq) = c;
  }
}

extern "C" void kernel_launch(void* const* d_in, const int* in_sizes, int n_in,
                              void* d_out, int out_size, void* d_ws,
                              size_t ws_size, hipStream_t stream) {
  const float* x = (const float*)d_in[0];
  const int* ei = (const int*)d_in[1];
  const float* mW1 = (const float*)d_in[2];
  const float* mb1 = (const float*)d_in[3];
  const float* mW2 = (const float*)d_in[4];
  const float* mb2 = (const float*)d_in[5];
  const float* mW3 = (const float*)d_in[6];
  const float* mb3 = (const float*)d_in[7];
  const float* oW1 = (const float*)d_in[8];
  const float* ob1 = (const float*)d_in[9];
  const float* oW2 = (const float*)d_in[10];
  const float* ob2 = (const float*)d_in[11];
  const float* oW3 = (const float*)d_in[12];
  const float* ob3 = (const float*)d_in[13];
  float* out = (float*)d_out;

  // d_out doubles as scratch for h1d (12.8MB f32) + h1s (6.4MB bf16): both are
  // fully consumed by edge_mfma before fused_tail overwrites out.
  float* h1d_buf = (float*)d_out;
  short* h1s_buf = (short*)((char*)d_out + (size_t)NP * HID * 4);

  // ws layout (~20.6MB; proven ws >= 33.3MB):
  // wq | gOff | binStart | co | csr_src | pairs/rsum (rsum aliases pairs)
  char* p = (char*)d_ws;
  short* wqs = (short*)p;            p += (size_t)WQ_FRAGS * 64 * 16;
  int* gOff = (int*)p;               p += (size_t)NBIN * NWG * 4;
  int* binStart = (int*)p;           p += 200 * 4;
  int2* co = (int2*)p;               p += (size_t)NP_PAD * 8;
  int* csr_src = (int*)p;            p += (size_t)NE * 4;
  unsigned* pairs = (unsigned*)p;
  float* rsum = (float*)p;           // aliases pairs (dead after bin_csr)

  setup_kernel<<<NWG + 1 + TILE_BLOCKS, 256, 0, stream>>>(
      x, ei, mW1, mb1, mW2, mW3, oW1, oW2, oW3, gOff, wqs, h1d_buf, h1s_buf);

  scan_bins_kernel<<<1, 256, 0, stream>>>(gOff, binStart);
  bin_scatter_kernel<<<NWG, 256, 0, stream>>>(ei, gOff, pairs);
  bin_csr_kernel<<<NBIN, 512, 0, stream>>>(pairs, binStart, co, csr_src);

  edge_mfma_kernel<<<2048, 256, 0, stream>>>(
      h1s_buf, h1d_buf, wqs, co, csr_src, mb2, rsum);

  fused_tail_kernel<<<TILE_BLOCKS, 256, 0, stream>>>(
      x, wqs, rsum, co, mb3, ob1, ob2, ob3, out);
}